// Round 7
// baseline (938.997 us; speedup 1.0000x reference)
//
#include <hip/hip_runtime.h>
#include <hip/hip_bf16.h>

// Problem constants
#define TT   128
#define BB   256
#define MM   512
#define GG   2560
#define K1P  960   // 940 padded to 960 (30 * 32)

typedef __attribute__((ext_vector_type(8))) short bf16x8;
typedef __attribute__((ext_vector_type(4))) short bf16x4;
typedef __attribute__((ext_vector_type(4))) float f32x4;
typedef __attribute__((ext_vector_type(4))) unsigned u32x4;
typedef __attribute__((ext_vector_type(2))) unsigned u32x2;

__device__ __forceinline__ float bf2f(unsigned short u){
  union { unsigned u; float f; } v; v.u = ((unsigned)u) << 16; return v.f;
}
__device__ __forceinline__ unsigned short f2bf(float f){
  union { float f; unsigned u; } v; v.f = f;
  unsigned r = v.u + 0x7fffu + ((v.u >> 16) & 1u);
  return (unsigned short)(r >> 16);
}
__device__ __forceinline__ float sigmoidf_(float x){ return 1.f/(1.f + __expf(-x)); }
__device__ __forceinline__ float tanhf_(float x){
  x = fminf(15.f, fmaxf(-15.f, x));
  float e = __expf(2.f*x);
  return (e - 1.f)/(e + 1.f);
}

// MALL-coherent (cross-XCD) accesses: sc0 sc1 bypass L1/L2; coherence point =
// Infinity Cache. No cache-maintenance fences needed.
__device__ __forceinline__ u32x4 load_coh16u(const void* p){
  u32x4 r;
  asm volatile("global_load_dwordx4 %0, %1, off sc0 sc1" : "=v"(r) : "v"(p) : "memory");
  return r;
}
__device__ __forceinline__ void store_coh8(void* p, u32x2 v){
  asm volatile("global_store_dwordx2 %0, %1, off sc0 sc1" :: "v"(p), "v"(v) : "memory");
}

// async global->LDS, 16B per lane; LDS dest = wave-uniform base + lane*16
__device__ __forceinline__ void gll16(const unsigned short* g, unsigned short* l){
  __builtin_amdgcn_global_load_lds(
      (const __attribute__((address_space(1))) void*)(g),
      (__attribute__((address_space(3))) void*)(l),
      16, 0, 0);
}

// ---------------- staging kernels ----------------

__global__ __launch_bounds__(256) void stage_a(const float* __restrict__ word,
                                               const float* __restrict__ tag,
                                               const float* __restrict__ rel,
                                               const float* __restrict__ kin,
                                               unsigned short* __restrict__ A){
  long id = (long)blockIdx.x * 256 + threadIdx.x;     // chunk over 32768*120
  int row = (int)(id / 120);
  int c8  = (int)(id % 120) * 8;
  bf16x8 o;
  #pragma unroll
  for (int j = 0; j < 8; ++j){
    int col = c8 + j; float v;
    if      (col < 300) v = word[(long)row*300 + col];
    else if (col < 364) v = tag [(long)row*64  + col-300];
    else if (col < 428) v = rel [(long)row*64  + col-364];
    else if (col < 940) v = kin [(long)row*512 + col-428];
    else v = 0.f;
    o[j] = (short)f2bf(v);
  }
  *reinterpret_cast<bf16x8*>(A + (long)row*K1P + c8) = o;
}

__global__ __launch_bounds__(256) void stage_wt(const float* __restrict__ Ww,
                                                const float* __restrict__ Wt,
                                                const float* __restrict__ Wr,
                                                const float* __restrict__ Wk,
                                                unsigned short* __restrict__ WT){
  long id = (long)blockIdx.x * 256 + threadIdx.x;   // 2560*960
  int kk = (int)(id % K1P);
  int n  = (int)(id / K1P);
  float v;
  if      (kk < 300) v = Ww[(long)kk*GG + n];
  else if (kk < 364) v = Wt[(long)(kk-300)*GG + n];
  else if (kk < 428) v = Wr[(long)(kk-364)*GG + n];
  else if (kk < 940) v = Wk[(long)(kk-428)*GG + n];
  else v = 0.f;
  WT[(long)n*K1P + kk] = f2bf(v);
}

__global__ __launch_bounds__(256) void stage_wht(const float* __restrict__ Wh,
                                                 unsigned short* __restrict__ WhT){
  long id = (long)blockIdx.x * 256 + threadIdx.x;   // 2560*512
  int kk = (int)(id % MM);
  int n  = (int)(id / MM);
  WhT[(long)n*MM + kk] = f2bf(Wh[(long)kk*GG + n]);
}

// h0 -> tagged arena buffer 0, tag=1:  arr[b*MM+m] = (1<<16) | bf16(h0)
__global__ __launch_bounds__(256) void init_h(const float* __restrict__ h0,
                                              unsigned* __restrict__ arr0){
  int id = blockIdx.x * 256 + threadIdx.x;          // 131072
  arr0[id] = (1u << 16) | (unsigned)f2bf(h0[id]);
}

// ---------------- xp GEMM: m97 structure (unchanged) ----------------
__global__ __launch_bounds__(256) void gemm_xp(const unsigned short* __restrict__ A,
                                               const unsigned short* __restrict__ WT,
                                               const float* __restrict__ bias,
                                               unsigned short* __restrict__ XP){
  __shared__ unsigned short As[128*32];   // 8 KB, linear [row][k]
  __shared__ unsigned short Bs[128*32];   // 8 KB, linear [ncol][k]
  const int tid  = threadIdx.x;
  const int wave = tid >> 6, lane = tid & 63;
  const int wr   = wave >> 1, wc = wave & 1;
  const int lrow = lane & 15, lhi = lane >> 4;
  const long row0 = (long)blockIdx.x * 128;
  const long col0 = (long)blockIdx.y * 128;

  const int sr0 = (wave*2 + 0)*16 + (lane >> 2);
  const int sr1 = (wave*2 + 1)*16 + (lane >> 2);
  const int sk  = (lane & 3) * 8;
  const unsigned short* ga0 = A  + (row0 + sr0)*K1P + sk;
  const unsigned short* ga1 = A  + (row0 + sr1)*K1P + sk;
  const unsigned short* gb0 = WT + (col0 + sr0)*K1P + sk;
  const unsigned short* gb1 = WT + (col0 + sr1)*K1P + sk;
  unsigned short* lA0 = As + (wave*2 + 0)*512;
  unsigned short* lA1 = As + (wave*2 + 1)*512;
  unsigned short* lB0 = Bs + (wave*2 + 0)*512;
  unsigned short* lB1 = Bs + (wave*2 + 1)*512;

  f32x4 acc[4][4] = {};
  for (int ks = 0; ks < 30; ++ks){
    const int k0 = ks * 32;
    __syncthreads();
    gll16(ga0 + k0, lA0);
    gll16(ga1 + k0, lA1);
    gll16(gb0 + k0, lB0);
    gll16(gb1 + k0, lB1);
    __syncthreads();
    bf16x8 af[4], bfr[4];
    #pragma unroll
    for (int mi = 0; mi < 4; ++mi)
      af[mi] = *reinterpret_cast<const bf16x8*>(As + (wr*64 + mi*16 + lrow)*32 + lhi*8);
    #pragma unroll
    for (int ni = 0; ni < 4; ++ni)
      bfr[ni] = *reinterpret_cast<const bf16x8*>(Bs + (wc*64 + ni*16 + lrow)*32 + lhi*8);
    #pragma unroll
    for (int mi = 0; mi < 4; ++mi)
      #pragma unroll
      for (int ni = 0; ni < 4; ++ni)
        acc[mi][ni] = __builtin_amdgcn_mfma_f32_16x16x32_bf16(af[mi], bfr[ni], acc[mi][ni], 0, 0, 0);
  }
  const int t     = (int)(row0 >> 8);
  const int brow0 = (int)(row0 & 255);
  #pragma unroll
  for (int ni = 0; ni < 4; ++ni){
    const int col = (int)col0 + wc*64 + ni*16 + lrow;
    const float bv = bias[col];
    #pragma unroll
    for (int mi = 0; mi < 4; ++mi){
      const int b4 = brow0 + wr*64 + mi*16 + lhi*4;
      bf16x4 pk;
      #pragma unroll
      for (int j = 0; j < 4; ++j) pk[j] = (short)f2bf(acc[mi][ni][j] + bv);
      *reinterpret_cast<bf16x4*>(XP + ((long)t*GG + col)*BB + b4) = pk;
    }
  }
}

// ---------------- fused persistent recurrence ----------------
// grid 256 x 256. Block = (bt 0..7) x (mc 0..31). K-split waves (R5).
// NEW: tagged-data exchange, NO barriers/flags. h ping-pong arena of u32
//   values (tag<<16)|h_bf16. Producer: one 8B sc0sc1 store per thread.
//   Consumer: per-lane poll-load own 16 u32x4 fragments until tags==t+1.
//   One MALL round-trip carries both "ready" and the data.
// Lap-safety: producer writes tag t+3 on a buffer only after consuming t+2
//   <= all blocks produced t+2 <= all consumed t+1 (exact-match tags).
// Replay-safety: arena memset(0) every launch; init_h writes tag 1.
__global__ __launch_bounds__(256, 1) void lstm_fused(const unsigned short* __restrict__ XP,
                                                     const float* __restrict__ q,
                                                     const unsigned short* __restrict__ WhT,
                                                     const float* __restrict__ c0,
                                                     unsigned* __restrict__ harr,
                                                     float* __restrict__ out){
  __shared__ float Part[4][5][2][16][20];        // [w][gate][rt][m][b pad20] 51.2 KB
  const int tid  = threadIdx.x;
  const int w    = tid >> 6, lane = tid & 63;
  const int lrow = lane & 15, lhi = lane >> 4;
  const int bt = blockIdx.x >> 5, mc = blockIdx.x & 31;
  const int b0 = bt * 32, m0 = mc * 16;

  // this wave's k-quarter of Wh for all 5 gates (80 VGPR)
  bf16x8 Breg[5][4];
  #pragma unroll
  for (int g = 0; g < 5; ++g)
    #pragma unroll
    for (int kf = 0; kf < 4; ++kf)
      Breg[g][kf] = *reinterpret_cast<const bf16x8*>(
          WhT + (long)(g*MM + m0 + lrow)*MM + w*128 + kf*32 + lhi*8);

  // update-phase mapping: 2 states per thread
  const int bl = tid >> 3, mi2 = (tid & 7) * 2;
  const int rt2 = bl >> 4, brow = bl & 15;
  const int gb = b0 + bl, gm = m0 + mi2;
  float cx = c0[(long)gb*MM + gm];
  float cy = c0[(long)gb*MM + gm + 1];

  // prefetch t=0 xp/q
  unsigned short xv[5][2]; float qx, qy;
  #pragma unroll
  for (int j = 0; j < 5; ++j){
    xv[j][0] = XP[((long)0*GG + j*MM + gm    )*BB + gb];
    xv[j][1] = XP[((long)0*GG + j*MM + gm + 1)*BB + gb];
  }
  qx = q[((long)0*BB + gb)*MM + gm];
  qy = q[((long)0*BB + gb)*MM + gm + 1];

  for (int t = 0; t < TT; ++t){
    // consumer: poll-load tagged h fragments (buffer t&1, tag t+1)
    const unsigned* hb = harr + (size_t)(t & 1) * (BB*MM);
    const unsigned etag = (unsigned)(t + 1);
    u32x4 tv[2][4][2];                       // [rt][kf][half of 8 k-elems]
    {
      unsigned spins = 0;
      for (;;){
        #pragma unroll
        for (int rt = 0; rt < 2; ++rt)
          #pragma unroll
          for (int kf = 0; kf < 4; ++kf){
            const unsigned* p = hb + (b0 + rt*16 + lrow)*MM + w*128 + kf*32 + lhi*8;
            tv[rt][kf][0] = load_coh16u(p);
            tv[rt][kf][1] = load_coh16u(p + 4);
          }
        asm volatile("s_waitcnt vmcnt(0)" ::: "memory");
        __builtin_amdgcn_sched_barrier(0);   // keep tag-check AFTER the wait
        unsigned diff = 0;
        #pragma unroll
        for (int rt = 0; rt < 2; ++rt)
          #pragma unroll
          for (int kf = 0; kf < 4; ++kf)
            #pragma unroll
            for (int h2 = 0; h2 < 2; ++h2){
              // tags per 8B store unit: elements 0 and 2 of each u32x4
              diff |= (tv[rt][kf][h2][0] >> 16) ^ etag;
              diff |= (tv[rt][kf][h2][2] >> 16) ^ etag;
            }
        if (diff == 0) break;
        if (++spins > (1u << 16)) break;     // safety valve
      }
    }
    // unpack low halves -> bf16x8 A-fragments
    bf16x8 af[2][4];
    #pragma unroll
    for (int rt = 0; rt < 2; ++rt)
      #pragma unroll
      for (int kf = 0; kf < 4; ++kf){
        union { bf16x8 v; unsigned u[4]; } uu;
        uu.u[0] = (tv[rt][kf][0][0] & 0xffffu) | (tv[rt][kf][0][1] << 16);
        uu.u[1] = (tv[rt][kf][0][2] & 0xffffu) | (tv[rt][kf][0][3] << 16);
        uu.u[2] = (tv[rt][kf][1][0] & 0xffffu) | (tv[rt][kf][1][1] << 16);
        uu.u[3] = (tv[rt][kf][1][2] & 0xffffu) | (tv[rt][kf][1][3] << 16);
        af[rt][kf] = uu.v;
      }

    // h @ Wh for this wave's k-quarter, all 5 gates x both row-tiles
    f32x4 acc[5][2] = {};
    #pragma unroll
    for (int kf = 0; kf < 4; ++kf)
      #pragma unroll
      for (int rt = 0; rt < 2; ++rt)
        #pragma unroll
        for (int g = 0; g < 5; ++g)
          acc[g][rt] = __builtin_amdgcn_mfma_f32_16x16x32_bf16(af[rt][kf], Breg[g][kf], acc[g][rt], 0, 0, 0);

    // publish k-partials (D: col=m=lrow, row=b=lhi*4+j -> [m][b] contiguous x4)
    #pragma unroll
    for (int g = 0; g < 5; ++g)
      #pragma unroll
      for (int rt = 0; rt < 2; ++rt)
        *reinterpret_cast<f32x4*>(&Part[w][g][rt][lrow][lhi*4]) = acc[g][rt];
    __syncthreads();                               // syncA: Part ready

    // k-reduction + gates for this thread's 2 states
    float gv[5][2];
    #pragma unroll
    for (int g = 0; g < 5; ++g)
      #pragma unroll
      for (int x = 0; x < 2; ++x)
        gv[g][x] = Part[0][g][rt2][mi2+x][brow] + Part[1][g][rt2][mi2+x][brow]
                 + Part[2][g][rt2][mi2+x][brow] + Part[3][g][rt2][mi2+x][brow]
                 + bf2f(xv[g][x]);
    const float qx_t = qx, qy_t = qy;

    // Part is reused next step; ensure reads done before next writes
    __syncthreads();                               // syncA2 (block-local only)

    // prefetch next step's xp/q
    if (t < TT - 1){
      #pragma unroll
      for (int j = 0; j < 5; ++j){
        xv[j][0] = XP[((long)(t+1)*GG + j*MM + gm    )*BB + gb];
        xv[j][1] = XP[((long)(t+1)*GG + j*MM + gm + 1)*BB + gb];
      }
      qx = q[((long)(t+1)*BB + gb)*MM + gm];
      qy = q[((long)(t+1)*BB + gb)*MM + gm + 1];
    }

    float hx, hy;
    {
      const float i_ = sigmoidf_(gv[0][0]);
      const float fd = sigmoidf_(gv[1][0]);
      const float fl = sigmoidf_(gv[2][0]);
      const float o_ = sigmoidf_(gv[3][0]);
      const float u_ = tanhf_(gv[4][0]);
      const float cn = i_*u_ + fd*qx_t + fl*cx;
      cx = cn; hx = o_*tanhf_(cn);
    }
    {
      const float i_ = sigmoidf_(gv[0][1]);
      const float fd = sigmoidf_(gv[1][1]);
      const float fl = sigmoidf_(gv[2][1]);
      const float o_ = sigmoidf_(gv[3][1]);
      const float u_ = tanhf_(gv[4][1]);
      const float cn = i_*u_ + fd*qy_t + fl*cy;
      cy = cn; hy = o_*tanhf_(cn);
    }

    if (t < TT - 1){
      // producer: one 8B tagged store (tag t+2) into buffer (t+1)&1
      unsigned* nb = harr + (size_t)((t + 1) & 1) * (BB*MM);
      const unsigned tg = (unsigned)(t + 2) << 16;
      u32x2 pv;
      pv[0] = tg | (unsigned)f2bf(hx);
      pv[1] = tg | (unsigned)f2bf(hy);
      store_coh8(nb + (long)gb*MM + gm, pv);
    } else {
      out[(long)gb*1024 + gm]           = hx;
      out[(long)gb*1024 + gm + 1]       = hy;
      out[(long)gb*1024 + 512 + gm]     = cx;
      out[(long)gb*1024 + 512 + gm + 1] = cy;
    }
  }
}

extern "C" void kernel_launch(void* const* d_in, const int* in_sizes, int n_in,
                              void* d_out, int out_size, void* d_ws, size_t ws_size,
                              hipStream_t stream){
  (void)in_sizes; (void)n_in; (void)out_size; (void)ws_size;
  const float* word = (const float*)d_in[0];
  const float* tag  = (const float*)d_in[1];
  const float* rel  = (const float*)d_in[2];
  const float* kin  = (const float*)d_in[3];
  const float* q    = (const float*)d_in[4];
  const float* h0   = (const float*)d_in[5];
  const float* c0   = (const float*)d_in[6];
  const float* Ww   = (const float*)d_in[7];
  const float* Wt   = (const float*)d_in[8];
  const float* Wr   = (const float*)d_in[9];
  const float* Wk   = (const float*)d_in[10];
  const float* Wh   = (const float*)d_in[11];
  const float* bias = (const float*)d_in[12];
  float* out = (float*)d_out;

  char* ws = (char*)d_ws;
  size_t off = 0;
  auto alloc = [&](size_t bytes)->void*{
    void* p = ws + off; off = (off + bytes + 255) & ~(size_t)255; return p;
  };
  unsigned short* Abf = (unsigned short*)alloc((size_t)TT*BB*K1P*2);   // 62.9 MB
  unsigned short* WT  = (unsigned short*)alloc((size_t)GG*K1P*2);      // 4.9 MB
  unsigned short* WhT = (unsigned short*)alloc((size_t)GG*MM*2);       // 2.6 MB
  unsigned short* XP  = (unsigned short*)alloc((size_t)TT*BB*GG*2);    // 167.8 MB
  unsigned*       harr= (unsigned*)alloc((size_t)2*BB*MM*4);           // 1 MB tagged ping-pong

  hipMemsetAsync(harr, 0, (size_t)2*BB*MM*4, stream);

  stage_a  <<<dim3((TT*BB*(K1P/8) + 255)/256), 256, 0, stream>>>(word, tag, rel, kin, Abf);
  stage_wt <<<dim3((GG*K1P + 255)/256),        256, 0, stream>>>(Ww, Wt, Wr, Wk, WT);
  stage_wht<<<dim3((GG*MM + 255)/256),         256, 0, stream>>>(Wh, WhT);
  init_h   <<<dim3((BB*MM + 255)/256),         256, 0, stream>>>(h0, harr);

  gemm_xp<<<dim3(TT*BB/128, GG/128), 256, 0, stream>>>(Abf, WT, bias, XP);

  lstm_fused<<<dim3(256), 256, 0, stream>>>(XP, q, WhT, c0, harr, out);
}

// Round 9
// 739.119 us; speedup vs baseline: 1.2704x; 1.2704x over previous
//
#include <hip/hip_runtime.h>
#include <hip/hip_bf16.h>

// Problem constants
#define TT   128
#define BB   256
#define MM   512
#define GG   2560
#define K1P  960   // 940 padded to 960 (30 * 32)

typedef __attribute__((ext_vector_type(8))) short bf16x8;
typedef __attribute__((ext_vector_type(4))) short bf16x4;
typedef __attribute__((ext_vector_type(4))) float f32x4;

__device__ __forceinline__ float bf2f(unsigned short u){
  union { unsigned u; float f; } v; v.u = ((unsigned)u) << 16; return v.f;
}
__device__ __forceinline__ unsigned short f2bf(float f){
  union { float f; unsigned u; } v; v.f = f;
  unsigned r = v.u + 0x7fffu + ((v.u >> 16) & 1u);
  return (unsigned short)(r >> 16);
}
__device__ __forceinline__ float sigmoidf_(float x){ return 1.f/(1.f + __expf(-x)); }
__device__ __forceinline__ float tanhf_(float x){
  x = fminf(15.f, fmaxf(-15.f, x));
  float e = __expf(2.f*x);
  return (e - 1.f)/(e + 1.f);
}

// ---- scoped memory helpers ----
// sc0 only : bypass L1, served by this XCD's L2 (intra-XCD exchange)
// sc0 sc1  : bypass L1+L2, coherence point = MALL (cross-XCD exchange)
// NOTE: fast mode must use sc0 for BOTH store and load (L2 updated/read in
// place). Mixing (sc1 store + sc0 load) can hit a stale L2 line.
__device__ __forceinline__ void store_coh4(void* p, unsigned v){
  asm volatile("global_store_dword %0, %1, off sc0 sc1" :: "v"(p), "v"(v) : "memory");
}
__device__ __forceinline__ unsigned load_coh_u32(const unsigned* p){
  unsigned r;
  asm volatile("global_load_dword %0, %1, off sc0 sc1" : "=v"(r) : "v"(p) : "memory");
  asm volatile("s_waitcnt vmcnt(0)" ::: "memory");
  return r;
}
__device__ __forceinline__ bf16x8 load_h16_f(const void* p){
  bf16x8 r;
  asm volatile("global_load_dwordx4 %0, %1, off sc0" : "=v"(r) : "v"(p) : "memory");
  return r;
}
__device__ __forceinline__ bf16x8 load_h16_s(const void* p){
  bf16x8 r;
  asm volatile("global_load_dwordx4 %0, %1, off sc0 sc1" : "=v"(r) : "v"(p) : "memory");
  return r;
}
__device__ __forceinline__ void store_h32_f(void* p, unsigned v){
  asm volatile("global_store_dword %0, %1, off sc0" :: "v"(p), "v"(v) : "memory");
}
__device__ __forceinline__ void store_h32_s(void* p, unsigned v){
  asm volatile("global_store_dword %0, %1, off sc0 sc1" :: "v"(p), "v"(v) : "memory");
}

// async global->LDS, 16B per lane; LDS dest = wave-uniform base + lane*16
__device__ __forceinline__ void gll16(const unsigned short* g, unsigned short* l){
  __builtin_amdgcn_global_load_lds(
      (const __attribute__((address_space(1))) void*)(g),
      (__attribute__((address_space(3))) void*)(l),
      16, 0, 0);
}

// ---------------- staging kernels ----------------

__global__ __launch_bounds__(256) void stage_a(const float* __restrict__ word,
                                               const float* __restrict__ tag,
                                               const float* __restrict__ rel,
                                               const float* __restrict__ kin,
                                               unsigned short* __restrict__ A){
  long id = (long)blockIdx.x * 256 + threadIdx.x;     // chunk over 32768*120
  int row = (int)(id / 120);
  int c8  = (int)(id % 120) * 8;
  bf16x8 o;
  #pragma unroll
  for (int j = 0; j < 8; ++j){
    int col = c8 + j; float v;
    if      (col < 300) v = word[(long)row*300 + col];
    else if (col < 364) v = tag [(long)row*64  + col-300];
    else if (col < 428) v = rel [(long)row*64  + col-364];
    else if (col < 940) v = kin [(long)row*512 + col-428];
    else v = 0.f;
    o[j] = (short)f2bf(v);
  }
  *reinterpret_cast<bf16x8*>(A + (long)row*K1P + c8) = o;
}

__global__ __launch_bounds__(256) void stage_wt(const float* __restrict__ Ww,
                                                const float* __restrict__ Wt,
                                                const float* __restrict__ Wr,
                                                const float* __restrict__ Wk,
                                                unsigned short* __restrict__ WT){
  long id = (long)blockIdx.x * 256 + threadIdx.x;   // 2560*960
  int kk = (int)(id % K1P);
  int n  = (int)(id / K1P);
  float v;
  if      (kk < 300) v = Ww[(long)kk*GG + n];
  else if (kk < 364) v = Wt[(long)(kk-300)*GG + n];
  else if (kk < 428) v = Wr[(long)(kk-364)*GG + n];
  else if (kk < 940) v = Wk[(long)(kk-428)*GG + n];
  else v = 0.f;
  WT[(long)n*K1P + kk] = f2bf(v);
}

__global__ __launch_bounds__(256) void stage_wht(const float* __restrict__ Wh,
                                                 unsigned short* __restrict__ WhT){
  long id = (long)blockIdx.x * 256 + threadIdx.x;   // 2560*512
  int kk = (int)(id % MM);
  int n  = (int)(id / MM);
  WhT[(long)n*MM + kk] = f2bf(Wh[(long)kk*GG + n]);
}

__global__ __launch_bounds__(256) void init_h(const float* __restrict__ h0,
                                              unsigned short* __restrict__ hb){
  int id = blockIdx.x * 256 + threadIdx.x;          // 131072
  hb[id] = f2bf(h0[id]);
}

// ---------------- xp GEMM: m97 structure (unchanged, proven) ----------------
__global__ __launch_bounds__(256) void gemm_xp(const unsigned short* __restrict__ A,
                                               const unsigned short* __restrict__ WT,
                                               const float* __restrict__ bias,
                                               unsigned short* __restrict__ XP){
  __shared__ unsigned short As[128*32];   // 8 KB, linear [row][k]
  __shared__ unsigned short Bs[128*32];   // 8 KB, linear [ncol][k]
  const int tid  = threadIdx.x;
  const int wave = tid >> 6, lane = tid & 63;
  const int wr   = wave >> 1, wc = wave & 1;
  const int lrow = lane & 15, lhi = lane >> 4;
  const long row0 = (long)blockIdx.x * 128;
  const long col0 = (long)blockIdx.y * 128;

  const int sr0 = (wave*2 + 0)*16 + (lane >> 2);
  const int sr1 = (wave*2 + 1)*16 + (lane >> 2);
  const int sk  = (lane & 3) * 8;
  const unsigned short* ga0 = A  + (row0 + sr0)*K1P + sk;
  const unsigned short* ga1 = A  + (row0 + sr1)*K1P + sk;
  const unsigned short* gb0 = WT + (col0 + sr0)*K1P + sk;
  const unsigned short* gb1 = WT + (col0 + sr1)*K1P + sk;
  unsigned short* lA0 = As + (wave*2 + 0)*512;
  unsigned short* lA1 = As + (wave*2 + 1)*512;
  unsigned short* lB0 = Bs + (wave*2 + 0)*512;
  unsigned short* lB1 = Bs + (wave*2 + 1)*512;

  f32x4 acc[4][4] = {};
  for (int ks = 0; ks < 30; ++ks){
    const int k0 = ks * 32;
    __syncthreads();
    gll16(ga0 + k0, lA0);
    gll16(ga1 + k0, lA1);
    gll16(gb0 + k0, lB0);
    gll16(gb1 + k0, lB1);
    __syncthreads();
    bf16x8 af[4], bfr[4];
    #pragma unroll
    for (int mi = 0; mi < 4; ++mi)
      af[mi] = *reinterpret_cast<const bf16x8*>(As + (wr*64 + mi*16 + lrow)*32 + lhi*8);
    #pragma unroll
    for (int ni = 0; ni < 4; ++ni)
      bfr[ni] = *reinterpret_cast<const bf16x8*>(Bs + (wc*64 + ni*16 + lrow)*32 + lhi*8);
    #pragma unroll
    for (int mi = 0; mi < 4; ++mi)
      #pragma unroll
      for (int ni = 0; ni < 4; ++ni)
        acc[mi][ni] = __builtin_amdgcn_mfma_f32_16x16x32_bf16(af[mi], bfr[ni], acc[mi][ni], 0, 0, 0);
  }
  const int t     = (int)(row0 >> 8);
  const int brow0 = (int)(row0 & 255);
  #pragma unroll
  for (int ni = 0; ni < 4; ++ni){
    const int col = (int)col0 + wc*64 + ni*16 + lrow;
    const float bv = bias[col];
    #pragma unroll
    for (int mi = 0; mi < 4; ++mi){
      const int b4 = brow0 + wr*64 + mi*16 + lhi*4;
      bf16x4 pk;
      #pragma unroll
      for (int j = 0; j < 4; ++j) pk[j] = (short)f2bf(acc[mi][ni][j] + bv);
      *reinterpret_cast<bf16x4*>(XP + ((long)t*GG + col)*BB + b4) = pk;
    }
  }
}

// ---------------- fused persistent recurrence ----------------
// grid 256 x 256. Block = (bt = blockIdx&7) x (mc = blockIdx>>3): under
// round-robin dispatch, group bt's 32 blocks co-locate on one XCD.
// One-time discovery verifies purity via HW_REG_XCC_ID + MALL registration.
//   fast (pure)  : h exchange sc0-only (own XCD L2, ~200cy RT)
//   slow (impure): h exchange sc0sc1 (MALL) == proven R5 path
// Barrier is ALWAYS the R5 MALL path (agent atomic + sc0sc1 poll) -> no
// livelock possible; a false-pure only corrupts h (absmax fail, bounded).
__global__ __launch_bounds__(256, 1) void lstm_fused(const unsigned short* __restrict__ XP,
                                                     const float* __restrict__ q,
                                                     const unsigned short* __restrict__ WhT,
                                                     const float* __restrict__ c0,
                                                     unsigned short* __restrict__ hb0,
                                                     unsigned short* __restrict__ hb1,
                                                     float* __restrict__ out,
                                                     unsigned* __restrict__ sync){
  __shared__ float Part[4][5][2][16][20];        // [w][gate][rt][m][b pad20] 51.2 KB
  const int tid  = threadIdx.x;
  const int w    = tid >> 6, lane = tid & 63;
  const int lrow = lane & 15, lhi = lane >> 4;
  const int bt = blockIdx.x & 7, mc = blockIdx.x >> 3;
  const int b0 = bt * 32, m0 = mc * 16;
  unsigned* cnt    = sync + bt * 64;             // per-step barrier counter (MALL)
  unsigned* regcnt = sync + 512 + bt * 64;       // registration counter
  unsigned* xccmap = sync + 1024;                // [256] block -> xcc

  // ---- one-time XCD-purity discovery (bounded: valves + MALL ops only) ----
  unsigned xcc;
  asm volatile("s_getreg_b32 %0, hwreg(HW_REG_XCC_ID)" : "=s"(xcc));
  if (tid == 0){
    store_coh4(xccmap + blockIdx.x, xcc);
    asm volatile("s_waitcnt vmcnt(0)" ::: "memory");
    __hip_atomic_fetch_add(regcnt, 1u, __ATOMIC_RELAXED, __HIP_MEMORY_SCOPE_AGENT);
    unsigned spins = 0;
    while (load_coh_u32(regcnt) < 32u){
      __builtin_amdgcn_s_sleep(1);
      if (++spins > (1u << 16)) break;           // cheap valve; miss -> slow path
    }
  }
  __syncthreads();
  unsigned mj = (lane < 32) ? load_coh_u32(xccmap + bt + 8*(lane & 31)) : xcc;
  const bool fast = (__ballot(mj == xcc) == ~0ull);

  // this wave's k-quarter of Wh for all 5 gates (80 VGPR)
  bf16x8 Breg[5][4];
  #pragma unroll
  for (int g = 0; g < 5; ++g)
    #pragma unroll
    for (int kf = 0; kf < 4; ++kf)
      Breg[g][kf] = *reinterpret_cast<const bf16x8*>(
          WhT + (long)(g*MM + m0 + lrow)*MM + w*128 + kf*32 + lhi*8);

  // update-phase mapping: 2 states per thread
  const int bl = tid >> 3, mi2 = (tid & 7) * 2;
  const int rt2 = bl >> 4, brow = bl & 15;
  const int gb = b0 + bl, gm = m0 + mi2;
  float cx = c0[(long)gb*MM + gm];
  float cy = c0[(long)gb*MM + gm + 1];

  // prefetch t=0 xp/q
  unsigned short xv[5][2]; float qx, qy;
  #pragma unroll
  for (int j = 0; j < 5; ++j){
    xv[j][0] = XP[((long)0*GG + j*MM + gm    )*BB + gb];
    xv[j][1] = XP[((long)0*GG + j*MM + gm + 1)*BB + gb];
  }
  qx = q[((long)0*BB + gb)*MM + gm];
  qy = q[((long)0*BB + gb)*MM + gm + 1];

  for (int t = 0; t < TT; ++t){
    const unsigned short* hc = (t & 1) ? hb1 : hb0;
    unsigned short*       hn = (t & 1) ? hb0 : hb1;

    // issue h fragment loads straight to regs, kf-major (oldest = kf0 pair)
    bf16x8 af[2][4];
    if (fast){
      #pragma unroll
      for (int kf = 0; kf < 4; ++kf)
        #pragma unroll
        for (int rt = 0; rt < 2; ++rt)
          af[rt][kf] = load_h16_f(hc + (long)(b0 + rt*16 + lrow)*MM + w*128 + kf*32 + lhi*8);
    } else {
      #pragma unroll
      for (int kf = 0; kf < 4; ++kf)
        #pragma unroll
        for (int rt = 0; rt < 2; ++rt)
          af[rt][kf] = load_h16_s(hc + (long)(b0 + rt*16 + lrow)*MM + w*128 + kf*32 + lhi*8);
    }

    // MFMA with counted waits; SB brackets stop MFMA hoisting past waits
    f32x4 acc[5][2] = {};
    #pragma unroll
    for (int kf = 0; kf < 4; ++kf){
      __builtin_amdgcn_sched_barrier(0);
      if      (kf == 0) asm volatile("s_waitcnt vmcnt(6)" ::: "memory");
      else if (kf == 1) asm volatile("s_waitcnt vmcnt(4)" ::: "memory");
      else if (kf == 2) asm volatile("s_waitcnt vmcnt(2)" ::: "memory");
      else              asm volatile("s_waitcnt vmcnt(0)" ::: "memory");
      __builtin_amdgcn_sched_barrier(0);
      #pragma unroll
      for (int rt = 0; rt < 2; ++rt)
        #pragma unroll
        for (int g = 0; g < 5; ++g)
          acc[g][rt] = __builtin_amdgcn_mfma_f32_16x16x32_bf16(af[rt][kf], Breg[g][kf], acc[g][rt], 0, 0, 0);
    }

    // publish k-partials (D: col=m=lrow, row=b=lhi*4+j -> [m][b] contiguous x4)
    #pragma unroll
    for (int g = 0; g < 5; ++g)
      #pragma unroll
      for (int rt = 0; rt < 2; ++rt)
        *reinterpret_cast<f32x4*>(&Part[w][g][rt][lrow][lhi*4]) = acc[g][rt];
    __syncthreads();                               // syncA: Part ready

    // k-reduction + gates for this thread's 2 states
    float gv[5][2];
    #pragma unroll
    for (int g = 0; g < 5; ++g)
      #pragma unroll
      for (int x = 0; x < 2; ++x)
        gv[g][x] = Part[0][g][rt2][mi2+x][brow] + Part[1][g][rt2][mi2+x][brow]
                 + Part[2][g][rt2][mi2+x][brow] + Part[3][g][rt2][mi2+x][brow]
                 + bf2f(xv[g][x]);

    float hx, hy;
    {
      const float i_ = sigmoidf_(gv[0][0]);
      const float fd = sigmoidf_(gv[1][0]);
      const float fl = sigmoidf_(gv[2][0]);
      const float o_ = sigmoidf_(gv[3][0]);
      const float u_ = tanhf_(gv[4][0]);
      const float cn = i_*u_ + fd*qx + fl*cx;
      cx = cn; hx = o_*tanhf_(cn);
    }
    {
      const float i_ = sigmoidf_(gv[0][1]);
      const float fd = sigmoidf_(gv[1][1]);
      const float fl = sigmoidf_(gv[2][1]);
      const float o_ = sigmoidf_(gv[3][1]);
      const float u_ = tanhf_(gv[4][1]);
      const float cn = i_*u_ + fd*qy + fl*cy;
      cy = cn; hy = o_*tanhf_(cn);
    }

    // store h EARLY (before prefetch) so the drain starts sooner
    const unsigned hv = (unsigned)f2bf(hx) | ((unsigned)f2bf(hy) << 16);
    if (t < TT - 1){
      if (fast) store_h32_f(hn + (long)gb*MM + gm, hv);
      else      store_h32_s(hn + (long)gb*MM + gm, hv);
    } else {
      out[(long)gb*1024 + gm]           = hx;
      out[(long)gb*1024 + gm + 1]       = hy;
      out[(long)gb*1024 + 512 + gm]     = cx;
      out[(long)gb*1024 + 512 + gm + 1] = cy;
    }

    // prefetch next step's xp/q (fills the barrier wait)
    if (t < TT - 1){
      #pragma unroll
      for (int j = 0; j < 5; ++j){
        xv[j][0] = XP[((long)(t+1)*GG + j*MM + gm    )*BB + gb];
        xv[j][1] = XP[((long)(t+1)*GG + j*MM + gm + 1)*BB + gb];
      }
      qx = q[((long)(t+1)*BB + gb)*MM + gm];
      qy = q[((long)(t+1)*BB + gb)*MM + gm + 1];
    }

    // per-bt barrier, ALWAYS MALL scope (proven): syncB drains all h stores
    // (fast: acked at L2; slow: at MALL) before tid0 arrives; tid0 polls.
    if (t != TT - 1){
      __syncthreads();                             // syncB
      if (tid == 0){
        __hip_atomic_fetch_add(cnt, 1u, __ATOMIC_RELAXED, __HIP_MEMORY_SCOPE_AGENT);
        const unsigned target = (unsigned)(t + 1) * 32u;
        unsigned spins = 0;
        while (load_coh_u32(cnt) < target){
          __builtin_amdgcn_s_sleep(1);
          if (++spins > (1u << 20)) break;         // safety valve
        }
      }
      __syncthreads();                             // syncC: release all waves
    }
  }
}

extern "C" void kernel_launch(void* const* d_in, const int* in_sizes, int n_in,
                              void* d_out, int out_size, void* d_ws, size_t ws_size,
                              hipStream_t stream){
  (void)in_sizes; (void)n_in; (void)out_size; (void)ws_size;
  const float* word = (const float*)d_in[0];
  const float* tag  = (const float*)d_in[1];
  const float* rel  = (const float*)d_in[2];
  const float* kin  = (const float*)d_in[3];
  const float* q    = (const float*)d_in[4];
  const float* h0   = (const float*)d_in[5];
  const float* c0   = (const float*)d_in[6];
  const float* Ww   = (const float*)d_in[7];
  const float* Wt   = (const float*)d_in[8];
  const float* Wr   = (const float*)d_in[9];
  const float* Wk   = (const float*)d_in[10];
  const float* Wh   = (const float*)d_in[11];
  const float* bias = (const float*)d_in[12];
  float* out = (float*)d_out;

  char* ws = (char*)d_ws;
  size_t off = 0;
  auto alloc = [&](size_t bytes)->void*{
    void* p = ws + off; off = (off + bytes + 255) & ~(size_t)255; return p;
  };
  unsigned short* Abf = (unsigned short*)alloc((size_t)TT*BB*K1P*2);   // 62.9 MB
  unsigned short* WT  = (unsigned short*)alloc((size_t)GG*K1P*2);      // 4.9 MB
  unsigned short* WhT = (unsigned short*)alloc((size_t)GG*MM*2);       // 2.6 MB
  unsigned short* XP  = (unsigned short*)alloc((size_t)TT*BB*GG*2);    // 167.8 MB
  unsigned short* hb0 = (unsigned short*)alloc((size_t)BB*MM*2);
  unsigned short* hb1 = (unsigned short*)alloc((size_t)BB*MM*2);
  unsigned*       syn = (unsigned*)alloc((size_t)(512 + 512 + 256)*4); // cnt|regcnt|xccmap

  hipMemsetAsync(syn, 0, (size_t)(512 + 512 + 256)*4, stream);

  stage_a  <<<dim3((TT*BB*(K1P/8) + 255)/256), 256, 0, stream>>>(word, tag, rel, kin, Abf);
  stage_wt <<<dim3((GG*K1P + 255)/256),        256, 0, stream>>>(Ww, Wt, Wr, Wk, WT);
  stage_wht<<<dim3((GG*MM + 255)/256),         256, 0, stream>>>(Wh, WhT);
  init_h   <<<dim3((BB*MM + 255)/256),         256, 0, stream>>>(h0, hb0);

  gemm_xp<<<dim3(TT*BB/128, GG/128), 256, 0, stream>>>(Abf, WT, bias, XP);

  lstm_fused<<<dim3(256), 256, 0, stream>>>(XP, q, WhT, c0, hb0, hb1, out, syn);
}